// Round 4
// baseline (121.104 us; speedup 1.0000x reference)
//
#include <hip/hip_runtime.h>

#define HH 260
#define WW 346
#define CC 1212            // real channel count (pred layout)
#define CP 1280            // padded compact space: [0,640) pol0, [640,1280) pol1
#define HALF 640
#define NA 606             // active channels per polarity (260 + 346)
#define BB 16
#define TT 4096
#define INV_TEMP (1.0f/256.0f)
#define KCH 256            // chunks per batch
#define LCH 16             // TT / KCH
#define NG 16              // groups per batch
#define GSZ 16             // chunks per group
#define GLEN (GSZ * LCH)   // 256 steps per group
#define NJ 10              // compact registers per polarity set (640/64)
#define SPLIT 4            // channel slices per group scan
#define SLICE (CP / SPLIT) // 320
#define SREG (SLICE / 64)  // 5

// ------ Fused phase 1+2a: lazy backward group scan -> LCin (per-chunk carries) + GroupL ------
__global__ __launch_bounds__(64) void p12_scan(const float* __restrict__ target,
                                               float* __restrict__ LCin,
                                               float* __restrict__ GroupL) {
    const int blk = blockIdx.x;            // (b*NG + g)*SPLIT + sl
    const int sl = blk & (SPLIT - 1);
    const int bg = blk >> 2;
    const int b = bg >> 4, g = bg & 15;
    const int lane = threadIdx.x;
    const int cbase = sl * SLICE;
    const int a0 = g * GLEN;

    __shared__ float tg[GLEN][4];
    __shared__ float tnextS;
    for (int idx = lane; idx < GLEN * 4; idx += 64)
        tg[idx >> 2][idx & 3] = target[((size_t)b * TT + a0) * 4 + idx];
    if (lane == 0) tnextS = (a0 + GLEN < TT) ? target[((size_t)b * TT + a0 + GLEN) * 4] : 0.0f;
    __syncthreads();

    float sig[SREG];
#pragma unroll
    for (int j = 0; j < SREG; ++j) sig[j] = 0.f;
    float D = 1.f;

    for (int k = GSZ - 1; k >= 0; --k) {
        // write carry entering chunk k (within-group suffix), and renormalize
        float* __restrict__ outp = LCin + ((size_t)(b * KCH + g * GSZ + k)) * CP + cbase;
#pragma unroll
        for (int j = 0; j < SREG; ++j) {
            sig[j] *= D;
            outp[lane + 64 * j] = sig[j];
        }
        D = 1.f;
        // process chunk k's steps backward
#pragma unroll
        for (int q = LCH - 1; q >= 0; --q) {
            const int li = k * LCH + q;
            const int i = a0 + li;
            const float ti = tg[li][0];
            const float tn = (li == GLEN - 1) ? tnextS : tg[li + 1][0];
            if (i < TT - 1) D *= __expf(-(tn - ti) * INV_TEMP);
            if (D < 1e-30f) {        // safety renorm (uniform, ~never taken)
#pragma unroll
                for (int j = 0; j < SREG; ++j) sig[j] *= D;
                D = 1.f;
            }
            const int y = __builtin_amdgcn_readfirstlane((int)tg[li][1]);
            const int x = __builtin_amdgcn_readfirstlane((int)tg[li][2]);
            const int p = __builtin_amdgcn_readfirstlane((int)tg[li][3]);
            const float inv = __frcp_rn(D);
            const int uy = p * HALF + y - cbase;
            const int ux = p * HALF + 260 + x - cbase;
            if ((unsigned)uy < (unsigned)SLICE) {
                const float add = (lane == (uy & 63)) ? inv : 0.f;
                const int r = uy >> 6;
                if (r == 0) sig[0] += add;
                else if (r == 1) sig[1] += add;
                else if (r == 2) sig[2] += add;
                else if (r == 3) sig[3] += add;
                else sig[4] += add;
            }
            if ((unsigned)ux < (unsigned)SLICE) {
                const float add = (lane == (ux & 63)) ? inv : 0.f;
                const int r = ux >> 6;
                if (r == 0) sig[0] += add;
                else if (r == 1) sig[1] += add;
                else if (r == 2) sig[2] += add;
                else if (r == 3) sig[3] += add;
                else sig[4] += add;
            }
        }
    }
    float* __restrict__ gout = GroupL + (size_t)bg * CP + cbase;
#pragma unroll
    for (int j = 0; j < SREG; ++j) gout[lane + 64 * j] = sig[j] * D;
}

// ------- Phase 2b: super-scan across 16 groups (preloaded, no dependent-load chain) -------
__global__ __launch_bounds__(256) void p2b(const float* __restrict__ target,
                                           const float* __restrict__ GroupL,
                                           float* __restrict__ SC) {
    const int blk = blockIdx.x;            // BB*5
    const int ct = blk % 5;
    const int b = blk / 5;
    const int c = ct * 256 + threadIdx.x;

    float Gv[NG], GP[NG];
#pragma unroll
    for (int g = 0; g < NG; ++g)
        Gv[g] = GroupL[((size_t)(b * NG + g)) * CP + c];
#pragma unroll
    for (int g = 0; g < NG; ++g) {
        if (g < NG - 1) {
            const float ta = target[((size_t)b * TT + g * GLEN) * 4];
            const float te = target[((size_t)b * TT + (g + 1) * GLEN) * 4];
            GP[g] = __expf(-(te - ta) * INV_TEMP);
        } else GP[g] = 0.f;
    }
    float carry = 0.f;
#pragma unroll
    for (int g = NG - 1; g >= 0; --g) {
        SC[((size_t)(b * NG + g)) * CP + c] = carry;
        carry = fmaf(GP[g], carry, Gv[g]);
    }
}

// ---------------- Phase 3: replay with true carry + fused loss ----------------
__global__ __launch_bounds__(64) void p3_loss(const float* __restrict__ pred,
                                              const float* __restrict__ target,
                                              const float* __restrict__ LCin,
                                              const float* __restrict__ SC,
                                              double* __restrict__ partials) {
    const int blk = blockIdx.x;
    const int b = blk >> 8, k = blk & (KCH - 1);
    const int g = k >> 4;
    const int a = k * LCH;
    const int lane = threadIdx.x;

    __shared__ float tg[LCH][4];
    __shared__ float tnextS;
    tg[lane >> 2][lane & 3] = target[((size_t)b * TT + a) * 4 + lane];
    if (lane == 0) tnextS = (a + LCH < TT) ? target[((size_t)b * TT + a + LCH) * 4] : 0.0f;
    __syncthreads();

    // carry(k) = LCin[k] + Qk * SC[group], Qk = exp(-(t[groupEnd] - t[a_{k+1}])/T)
    float Qk = 0.f;
    if (g < NG - 1) {
        const float tge = target[((size_t)b * TT + (g + 1) * GLEN) * 4];
        const float tk1 = target[((size_t)b * TT + (k + 1) * LCH) * 4];
        Qk = __expf(-(tge - tk1) * INV_TEMP);
    }

    const float* __restrict__ lc = LCin + (size_t)blk * CP;
    const float* __restrict__ sc = SC + ((size_t)(b * NG + g)) * CP;
    float s0[NJ], s1[NJ];
#pragma unroll
    for (int j = 0; j < NJ; ++j) {
        const int u = lane + 64 * j;
        s0[j] = fmaf(Qk, sc[u], lc[u]);
        s1[j] = fmaf(Qk, sc[HALF + u], lc[HALF + u]);
    }

    float prA[NJ], prB[NJ];
    {
        const int p = (int)tg[LCH - 1][3];
        const float* __restrict__ prow = pred + ((size_t)b * TT + a + LCH - 1) * CC;
#pragma unroll
        for (int j = 0; j < NJ; ++j) {
            const int u = lane + 64 * j;
            const int c = (u < 260) ? p * HH + u : 2 * HH + p * WW + (u - 260);
            prA[j] = (u < NA) ? prow[c] : 0.0f;
        }
    }

    double lacc = 0.0;
    for (int li = LCH - 1; li >= 0; --li) {
        if (li > 0) {
            const int pn = (int)tg[li - 1][3];
            const float* __restrict__ prow = pred + ((size_t)b * TT + a + li - 1) * CC;
#pragma unroll
            for (int j = 0; j < NJ; ++j) {
                const int u = lane + 64 * j;
                const int c = (u < 260) ? pn * HH + u : 2 * HH + pn * WW + (u - 260);
                prB[j] = (u < NA) ? prow[c] : 0.0f;
            }
        }

        const int i = a + li;
        const float ti = tg[li][0];
        const float tn = (li == LCH - 1) ? tnextS : tg[li + 1][0];
        const float d = (i == 0 || i >= TT - 1) ? 0.0f : __expf(-(tn - ti) * INV_TEMP);
        const int y = (int)tg[li][1], x = (int)tg[li][2], p = (int)tg[li][3];
        const int uy = y, ux = 260 + x;

        float zpy = 0.f, zsy = 0.f, dty = 0.f;
        float zpx = 0.f, zsx = 0.f, dtx = 0.f;

        auto stepActive = [&](float (&SA)[NJ], float (&SO)[NJ]) {
#pragma unroll
            for (int j = 0; j < NJ; ++j) {
                const int u = lane + 64 * j;
                const float add = (u == uy ? 1.f : 0.f) + (u == ux ? 1.f : 0.f);
                SA[j] = fmaf(SA[j], d, add);
                SO[j] *= d;
                float es = __expf(SA[j]);
                float ep = __expf(prA[j]);
                if (j == NJ - 1) {               // mask pad lanes (u >= 606)
                    const float m = (u < NA) ? 1.f : 0.f;
                    es *= m; ep *= m;
                }
                if (j < 4) {                     // u <= 255: pure y
                    zpy += ep; zsy += es; dty = fmaf(es, prA[j], dty);
                } else if (j == 4) {             // u in [256,320): mixed at 260
                    const bool isY = (u < 260);
                    zpy += isY ? ep : 0.f;
                    zsy += isY ? es : 0.f;
                    dty = fmaf(isY ? es : 0.f, prA[j], dty);
                    zpx += isY ? 0.f : ep;
                    zsx += isY ? 0.f : es;
                    dtx = fmaf(isY ? 0.f : es, prA[j], dtx);
                } else {                         // pure x
                    zpx += ep; zsx += es; dtx = fmaf(es, prA[j], dtx);
                }
            }
        };
        if (p == 0) stepActive(s0, s1); else stepActive(s1, s0);

#pragma unroll
        for (int off = 32; off > 0; off >>= 1) {
            zpy += __shfl_xor(zpy, off);
            zsy += __shfl_xor(zsy, off);
            dty += __shfl_xor(dty, off);
            zpx += __shfl_xor(zpx, off);
            zsx += __shfl_xor(zsx, off);
            dtx += __shfl_xor(dtx, off);
        }
        const float loss = __logf(zpy) + __logf(zpx)
                         - __fdividef(dty, zsy) - __fdividef(dtx, zsx);
        lacc += (double)loss;

#pragma unroll
        for (int j = 0; j < NJ; ++j) prA[j] = prB[j];
    }
    if (lane == 0) partials[blk] = lacc;
}

// ---------------- Finalize ----------------
__global__ void p4_final(const double* __restrict__ partials, float* __restrict__ out) {
    const int tid = threadIdx.x;   // 256
    double sum = 0.0;
    for (int i = tid; i < BB * KCH; i += 256) sum += partials[i];
#pragma unroll
    for (int off = 32; off > 0; off >>= 1) sum += __shfl_xor(sum, off);
    __shared__ double sred[4];
    if ((tid & 63) == 0) sred[tid >> 6] = sum;
    __syncthreads();
    if (tid == 0)
        out[0] = (float)((sred[0] + sred[1] + sred[2] + sred[3]) / (double)((size_t)BB * TT));
}

extern "C" void kernel_launch(void* const* d_in, const int* in_sizes, int n_in,
                              void* d_out, int out_size, void* d_ws, size_t ws_size,
                              hipStream_t stream) {
    const float* pred   = (const float*)d_in[0];
    const float* target = (const float*)d_in[1];
    float* out = (float*)d_out;

    // ws layout: [partials 4096 doubles (pad 64KB)][LCin][GroupL][SC]
    double* partials = (double*)d_ws;
    float* LCin   = (float*)((char*)d_ws + 65536);
    float* GroupL = LCin + (size_t)BB * KCH * CP;
    float* SC     = GroupL + (size_t)BB * NG * CP;

    p12_scan<<<BB * NG * SPLIT, 64, 0, stream>>>(target, LCin, GroupL);
    p2b<<<BB * 5, 256, 0, stream>>>(target, GroupL, SC);
    p3_loss<<<BB * KCH, 64, 0, stream>>>(pred, target, LCin, SC, partials);
    p4_final<<<1, 256, 0, stream>>>(partials, out);
}

// Round 5
// 82.132 us; speedup vs baseline: 1.4745x; 1.4745x over previous
//
#include <hip/hip_runtime.h>

#define HH 260
#define WW 346
#define CC 1212            // real channel count (pred layout)
#define CP 1280            // padded compact space: [0,640) pol0, [640,1280) pol1
#define HALF 640
#define NA 606             // active channels per polarity (260 + 346)
#define BB 16
#define TT 4096
#define INV_TEMP (1.0f/256.0f)
#define KCH 256            // chunks per batch
#define LCH 16             // TT / KCH
#define NG 16              // groups per batch
#define GSZ 16             // chunks per group
#define GLEN (GSZ * LCH)   // 256
#define NJ 10              // compact registers per polarity set (640/64)

// ---------------- Phase 1: per-chunk local state (zero carry), 4 chunks/block ----------------
__global__ __launch_bounds__(256) void p1_local(const float* __restrict__ target,
                                                float* __restrict__ Lbuf) {
    const int blk = blockIdx.x;            // BB*KCH/4
    const int b = blk >> 6;
    const int k0 = (blk & 63) << 2;
    const int tid = threadIdx.x;
    const int w = tid >> 6, lane = tid & 63;
    const int k = k0 + w;
    const int a = k * LCH;

    __shared__ float tg[4][LCH][4];
    __shared__ float tnextS[4];
    tg[tid >> 6][(tid >> 2) & 15][tid & 3] =
        target[((size_t)b * TT + k0 * LCH) * 4 + tid];
    if (tid < 4) {
        const int kk = k0 + tid;
        tnextS[tid] = (kk < KCH - 1) ? target[((size_t)b * TT + (kk + 1) * LCH) * 4] : 0.0f;
    }
    __syncthreads();

    float s0[NJ], s1[NJ];
#pragma unroll
    for (int j = 0; j < NJ; ++j) { s0[j] = 0.f; s1[j] = 0.f; }

    for (int li = LCH - 1; li >= 0; --li) {
        const int i = a + li;
        const float ti = tg[w][li][0];
        const float tn = (li == LCH - 1) ? tnextS[w] : tg[w][li + 1][0];
        const float d = (i >= TT - 1) ? 0.0f : __expf(-(tn - ti) * INV_TEMP);
        const int y = (int)tg[w][li][1], x = (int)tg[w][li][2], p = (int)tg[w][li][3];
        const int uy = y, ux = 260 + x;
        if (p == 0) {
#pragma unroll
            for (int j = 0; j < NJ; ++j) {
                const int u = lane + 64 * j;
                const float add = (u == uy ? 1.f : 0.f) + (u == ux ? 1.f : 0.f);
                s0[j] = fmaf(s0[j], d, add);
                s1[j] *= d;
            }
        } else {
#pragma unroll
            for (int j = 0; j < NJ; ++j) {
                const int u = lane + 64 * j;
                const float add = (u == uy ? 1.f : 0.f) + (u == ux ? 1.f : 0.f);
                s1[j] = fmaf(s1[j], d, add);
                s0[j] *= d;
            }
        }
    }
    float* __restrict__ out = Lbuf + (size_t)(b * KCH + k) * CP;
#pragma unroll
    for (int j = 0; j < NJ; ++j) {
        out[lane + 64 * j] = s0[j];
        out[HALF + lane + 64 * j] = s1[j];
    }
}

// ------- Phase 2a: within-group (16 chunks) suffix combine -------
__global__ __launch_bounds__(256) void p2a(const float* __restrict__ target,
                                           const float* __restrict__ Lbuf,
                                           float* __restrict__ LCin,
                                           float* __restrict__ GroupL) {
    const int blk = blockIdx.x;            // BB*NG*5
    const int ct = blk % 5;
    const int bg = blk / 5;                // b*NG + g
    const int b = bg >> 4, g = bg & 15;
    const int c = ct * 256 + threadIdx.x;  // < CP

    float carry = 0.f;
#pragma unroll
    for (int kk = GSZ - 1; kk >= 0; --kk) {
        const int k = g * GSZ + kk;
        const size_t idx = ((size_t)(b * KCH + k)) * CP + c;
        LCin[idx] = carry;
        float P = 0.f;
        if (k < KCH - 1) {
            const float ta = target[((size_t)b * TT + k * LCH) * 4];
            const float te = target[((size_t)b * TT + (k + 1) * LCH) * 4];
            P = __expf(-(te - ta) * INV_TEMP);
        }
        carry = fmaf(P, carry, Lbuf[idx]);
    }
    GroupL[(size_t)bg * CP + c] = carry;
}

// ------- Phase 2b: super-scan across 16 groups (preloaded) -------
__global__ __launch_bounds__(256) void p2b(const float* __restrict__ target,
                                           const float* __restrict__ GroupL,
                                           float* __restrict__ SC) {
    const int blk = blockIdx.x;            // BB*5
    const int ct = blk % 5;
    const int b = blk / 5;
    const int c = ct * 256 + threadIdx.x;

    float Gv[NG], GP[NG];
#pragma unroll
    for (int g = 0; g < NG; ++g)
        Gv[g] = GroupL[((size_t)(b * NG + g)) * CP + c];
#pragma unroll
    for (int g = 0; g < NG; ++g) {
        if (g < NG - 1) {
            const float ta = target[((size_t)b * TT + g * GLEN) * 4];
            const float te = target[((size_t)b * TT + (g + 1) * GLEN) * 4];
            GP[g] = __expf(-(te - ta) * INV_TEMP);
        } else GP[g] = 0.f;
    }
    float carry = 0.f;
#pragma unroll
    for (int g = NG - 1; g >= 0; --g) {
        SC[((size_t)(b * NG + g)) * CP + c] = carry;
        carry = fmaf(GP[g], carry, Gv[g]);
    }
}

// ---------------- Phase 3: replay with true carry + fused loss, 4 chunks/block ----------------
__global__ __launch_bounds__(256, 6) void p3_loss(const float* __restrict__ pred,
                                                  const float* __restrict__ target,
                                                  const float* __restrict__ LCin,
                                                  const float* __restrict__ SC,
                                                  double* __restrict__ partials) {
    const int blk = blockIdx.x;            // BB*KCH/4
    const int b = blk >> 6;
    const int k0 = (blk & 63) << 2;
    const int tid = threadIdx.x;
    const int w = tid >> 6, lane = tid & 63;
    const int k = k0 + w;
    const int g = k >> 4;
    const int a = k * LCH;

    __shared__ float tg[4][LCH][4];
    __shared__ float tnextS[4];
    tg[tid >> 6][(tid >> 2) & 15][tid & 3] =
        target[((size_t)b * TT + k0 * LCH) * 4 + tid];
    if (tid < 4) {
        const int kk = k0 + tid;
        tnextS[tid] = (kk < KCH - 1) ? target[((size_t)b * TT + (kk + 1) * LCH) * 4] : 0.0f;
    }
    __syncthreads();

    // carry(k) = LCin[k] + Qk * SC[group], Qk = exp(-(t[groupEnd] - t[a_{k+1}])/T)
    float Qk = 0.f;
    if (g < NG - 1) {
        const float tge = target[((size_t)b * TT + (g + 1) * GLEN) * 4];
        const float tk1 = target[((size_t)b * TT + (k + 1) * LCH) * 4];
        Qk = __expf(-(tge - tk1) * INV_TEMP);
    }

    const float* __restrict__ lc = LCin + (size_t)(b * KCH + k) * CP;
    const float* __restrict__ sc = SC + ((size_t)(b * NG + g)) * CP;
    float s0[NJ], s1[NJ];
#pragma unroll
    for (int j = 0; j < NJ; ++j) {
        const int u = lane + 64 * j;
        s0[j] = fmaf(Qk, sc[u], lc[u]);
        s1[j] = fmaf(Qk, sc[HALF + u], lc[HALF + u]);
    }

    float prA[NJ], prB[NJ];
    {
        const int p = (int)tg[w][LCH - 1][3];
        const float* __restrict__ prow = pred + ((size_t)b * TT + a + LCH - 1) * CC;
#pragma unroll
        for (int j = 0; j < NJ; ++j) {
            const int u = lane + 64 * j;
            const int c = (u < 260) ? p * HH + u : 2 * HH + p * WW + (u - 260);
            prA[j] = (u < NA) ? prow[c] : 0.0f;
        }
    }

    double lacc = 0.0;
    for (int li = LCH - 1; li >= 0; --li) {
        if (li > 0) {
            const int pn = (int)tg[w][li - 1][3];
            const float* __restrict__ prow = pred + ((size_t)b * TT + a + li - 1) * CC;
#pragma unroll
            for (int j = 0; j < NJ; ++j) {
                const int u = lane + 64 * j;
                const int c = (u < 260) ? pn * HH + u : 2 * HH + pn * WW + (u - 260);
                prB[j] = (u < NA) ? prow[c] : 0.0f;
            }
        }

        const int i = a + li;
        const float ti = tg[w][li][0];
        const float tn = (li == LCH - 1) ? tnextS[w] : tg[w][li + 1][0];
        const float d = (i == 0 || i >= TT - 1) ? 0.0f : __expf(-(tn - ti) * INV_TEMP);
        const int y = (int)tg[w][li][1], x = (int)tg[w][li][2], p = (int)tg[w][li][3];
        const int uy = y, ux = 260 + x;

        float zpy = 0.f, zsy = 0.f, dty = 0.f;
        float zpx = 0.f, zsx = 0.f, dtx = 0.f;

        auto stepActive = [&](float (&SA)[NJ], float (&SO)[NJ]) {
#pragma unroll
            for (int j = 0; j < NJ; ++j) {
                const int u = lane + 64 * j;
                const float add = (u == uy ? 1.f : 0.f) + (u == ux ? 1.f : 0.f);
                SA[j] = fmaf(SA[j], d, add);
                SO[j] *= d;
                float es = __expf(SA[j]);
                float ep = __expf(prA[j]);
                if (j == NJ - 1) {               // mask pad lanes (u >= 606)
                    const float m = (u < NA) ? 1.f : 0.f;
                    es *= m; ep *= m;
                }
                if (j < 4) {                     // u <= 255: pure y
                    zpy += ep; zsy += es; dty = fmaf(es, prA[j], dty);
                } else if (j == 4) {             // u in [256,320): mixed at 260
                    const bool isY = (u < 260);
                    zpy += isY ? ep : 0.f;
                    zsy += isY ? es : 0.f;
                    dty = fmaf(isY ? es : 0.f, prA[j], dty);
                    zpx += isY ? 0.f : ep;
                    zsx += isY ? 0.f : es;
                    dtx = fmaf(isY ? 0.f : es, prA[j], dtx);
                } else {                         // pure x
                    zpx += ep; zsx += es; dtx = fmaf(es, prA[j], dtx);
                }
            }
        };
        if (p == 0) stepActive(s0, s1); else stepActive(s1, s0);

#pragma unroll
        for (int off = 32; off > 0; off >>= 1) {
            zpy += __shfl_xor(zpy, off);
            zsy += __shfl_xor(zsy, off);
            dty += __shfl_xor(dty, off);
            zpx += __shfl_xor(zpx, off);
            zsx += __shfl_xor(zsx, off);
            dtx += __shfl_xor(dtx, off);
        }
        const float loss = __logf(zpy) + __logf(zpx)
                         - __fdividef(dty, zsy) - __fdividef(dtx, zsx);
        lacc += (double)loss;

#pragma unroll
        for (int j = 0; j < NJ; ++j) prA[j] = prB[j];
    }
    if (lane == 0) partials[b * KCH + k] = lacc;
}

// ---------------- Finalize ----------------
__global__ void p4_final(const double* __restrict__ partials, float* __restrict__ out) {
    const int tid = threadIdx.x;   // 256
    double sum = 0.0;
    for (int i = tid; i < BB * KCH; i += 256) sum += partials[i];
#pragma unroll
    for (int off = 32; off > 0; off >>= 1) sum += __shfl_xor(sum, off);
    __shared__ double sred[4];
    if ((tid & 63) == 0) sred[tid >> 6] = sum;
    __syncthreads();
    if (tid == 0)
        out[0] = (float)((sred[0] + sred[1] + sred[2] + sred[3]) / (double)((size_t)BB * TT));
}

extern "C" void kernel_launch(void* const* d_in, const int* in_sizes, int n_in,
                              void* d_out, int out_size, void* d_ws, size_t ws_size,
                              hipStream_t stream) {
    const float* pred   = (const float*)d_in[0];
    const float* target = (const float*)d_in[1];
    float* out = (float*)d_out;

    // ws layout: [partials 4096 doubles (pad 64KB)][Lbuf][LCin][GroupL][SC]
    double* partials = (double*)d_ws;
    float* Lbuf   = (float*)((char*)d_ws + 65536);
    float* LCin   = Lbuf + (size_t)BB * KCH * CP;
    float* GroupL = LCin + (size_t)BB * KCH * CP;
    float* SC     = GroupL + (size_t)BB * NG * CP;

    p1_local<<<BB * KCH / 4, 256, 0, stream>>>(target, Lbuf);
    p2a<<<BB * NG * 5, 256, 0, stream>>>(target, Lbuf, LCin, GroupL);
    p2b<<<BB * 5, 256, 0, stream>>>(target, GroupL, SC);
    p3_loss<<<BB * KCH / 4, 256, 0, stream>>>(pred, target, LCin, SC, partials);
    p4_final<<<1, 256, 0, stream>>>(partials, out);
}